// Round 1
// baseline (329.660 us; speedup 1.0000x reference)
//
#include <hip/hip_runtime.h>
#include <hip/hip_bf16.h>

#define NN 8192
#define NHEADS 4
#define OUTF 64
#define LOG2E 1.4426950408889634f

typedef __bf16 bf16x8 __attribute__((ext_vector_type(8)));
typedef float fx4 __attribute__((ext_vector_type(4)));
typedef int ix4 __attribute__((ext_vector_type(4)));
typedef unsigned short ushort8 __attribute__((ext_vector_type(8)));

// ---------------------------------------------------------------------------
// Kernel 1: Wh = h @ W[hd]  (fp32), emit:
//   - esrc[hd][i] = (Wh[i]·a1[hd]) * log2e
//   - edst[hd][i] = (Wh[i]·a2[hd]) * log2e
//   - whsw: bf16 Wh^T pre-swizzled into MFMA-16x16x32 B-fragment order:
//       idx = hd*524288 + (j>>5)*2048 + (f>>4)*512 + ((f&15) + 16*((j>>3)&3))*8 + (j&7)
// ---------------------------------------------------------------------------
__global__ __launch_bounds__(256) void k_wh(
    const float* __restrict__ h, const float* __restrict__ W,
    const float* __restrict__ a1, const float* __restrict__ a2,
    unsigned short* __restrict__ whsw, float* __restrict__ esrc,
    float* __restrict__ edst)
{
  __shared__ float ws[64 * 260];  // W[hd] transposed: ws[o*260 + k]
  const int tid = threadIdx.x;
  const int hd = blockIdx.x >> 7;
  const int i0 = (blockIdx.x & 127) << 6;   // 64 rows per block

  const float* Wp = W + hd * (256 * 64);
  for (int idx = tid; idx < 256 * 64; idx += 256) {
    int k = idx >> 6, o = idx & 63;
    ws[o * 260 + k] = Wp[idx];
  }
  __syncthreads();

  const int w = tid >> 6, o = tid & 63;     // wave w handles rows ibase..ibase+15, col o
  const int ibase = i0 + w * 16;
  float acc[16];
#pragma unroll
  for (int m = 0; m < 16; ++m) acc[m] = 0.f;

  const float* hp = h + (size_t)ibase * 256;
  for (int k4 = 0; k4 < 64; ++k4) {
    fx4 wv = *(const fx4*)(&ws[o * 260 + k4 * 4]);
#pragma unroll
    for (int m = 0; m < 16; ++m) {
      fx4 hv = *(const fx4*)(hp + m * 256 + k4 * 4);
      acc[m] += hv[0] * wv[0] + hv[1] * wv[1] + hv[2] * wv[2] + hv[3] * wv[3];
    }
  }

  // esrc / edst: reduce over o (the 64 lanes)
  const float a1v = a1[hd * 64 + o], a2v = a2[hd * 64 + o];
#pragma unroll
  for (int m = 0; m < 16; ++m) {
    float s1 = acc[m] * a1v, s2 = acc[m] * a2v;
#pragma unroll
    for (int d = 1; d < 64; d <<= 1) {
      s1 += __shfl_xor(s1, d);
      s2 += __shfl_xor(s2, d);
    }
    if (o == 0) {
      esrc[hd * NN + ibase + m] = s1 * LOG2E;
      edst[hd * NN + ibase + m] = s2 * LOG2E;
    }
  }

  // swizzled bf16 store of Wh (rows ibase..+15, col o)
  size_t base = (size_t)hd * 524288 + (size_t)((i0 >> 5) + (w >> 1)) * 2048 +
                (size_t)(o >> 4) * 512;
  int ln0 = (o & 15) + 16 * ((w & 1) * 2);
  ushort8 pk0, pk1;
#pragma unroll
  for (int m = 0; m < 8; ++m) {
    pk0[m] = __builtin_bit_cast(unsigned short, (__bf16)acc[m]);
    pk1[m] = __builtin_bit_cast(unsigned short, (__bf16)acc[m + 8]);
  }
  *(ushort8*)(whsw + base + (size_t)ln0 * 8) = pk0;
  *(ushort8*)(whsw + base + (size_t)(ln0 + 16) * 8) = pk1;
}

// ---------------------------------------------------------------------------
// Kernel 2: flash-style masked softmax + PV via mfma_f32_16x16x32_bf16.
// Block = 4 waves (one per head), 16 query rows per block.
// Lane layout (A-frag of 16x16x32): i = lane&15, j = jb + 8*(lane>>4) + e.
// No max-subtraction (logits O(10)): p = exp2(leakyrelu-scaled logit), masked.
// ---------------------------------------------------------------------------
struct Tile {
  ix4 a0, a1;
  fx4 e0, e1;
  bf16x8 b0, b1, b2, b3;
};

__device__ __forceinline__ void load_tile(Tile& t, const int* ar, const float* ep,
                                          const unsigned short* wp, int jb)
{
  t.a0 = *(const ix4*)(ar + jb);
  t.a1 = *(const ix4*)(ar + jb + 4);
  t.e0 = *(const fx4*)(ep + jb);
  t.e1 = *(const fx4*)(ep + jb + 4);
  const unsigned short* wq = wp + (size_t)(jb >> 5) * 2048;
  t.b0 = *(const bf16x8*)(wq);
  t.b1 = *(const bf16x8*)(wq + 512);
  t.b2 = *(const bf16x8*)(wq + 1024);
  t.b3 = *(const bf16x8*)(wq + 1536);
}

__device__ __forceinline__ void compute_tile(const Tile& t, float es, float& rsum,
                                             fx4* acc)
{
  float p[8];
#pragma unroll
  for (int e = 0; e < 8; ++e) {
    float ed = (e < 4) ? t.e0[e] : t.e1[e - 4];
    int av = (e < 4) ? t.a0[e] : t.a1[e - 4];
    float x = es + ed;                 // already scaled by log2e
    float lr = fmaxf(x, 0.2f * x);     // leakyrelu (valid for alpha in (0,1))
    float pe = __builtin_amdgcn_exp2f(lr);
    pe = (av > 0) ? pe : 0.0f;
    p[e] = pe;
  }
  rsum += ((p[0] + p[1]) + (p[2] + p[3])) + ((p[4] + p[5]) + (p[6] + p[7]));
  bf16x8 af;
#pragma unroll
  for (int e = 0; e < 8; ++e) af[e] = (__bf16)p[e];
  acc[0] = __builtin_amdgcn_mfma_f32_16x16x32_bf16(af, t.b0, acc[0], 0, 0, 0);
  acc[1] = __builtin_amdgcn_mfma_f32_16x16x32_bf16(af, t.b1, acc[1], 0, 0, 0);
  acc[2] = __builtin_amdgcn_mfma_f32_16x16x32_bf16(af, t.b2, acc[2], 0, 0, 0);
  acc[3] = __builtin_amdgcn_mfma_f32_16x16x32_bf16(af, t.b3, acc[3], 0, 0, 0);
}

__global__ __launch_bounds__(256) void k_attn(
    const int* __restrict__ adj, const unsigned short* __restrict__ whsw,
    const float* __restrict__ esrc, const float* __restrict__ edst,
    float* __restrict__ atted)
{
  const int lane = threadIdx.x & 63;
  const int hd = threadIdx.x >> 6;          // wave = head
  const int i0 = blockIdx.x << 4;           // 16 query rows per block
  const int il = lane & 15;
  const int g = lane >> 4;

  const float es = esrc[hd * NN + i0 + il];
  const int* ar = adj + (size_t)(i0 + il) * NN + g * 8;
  const float* ep = edst + hd * NN + g * 8;
  const unsigned short* wp = whsw + (size_t)hd * 524288 + (size_t)lane * 8;

  fx4 acc[4] = {};
  float rsum = 0.f;

  Tile t0, t1;
  load_tile(t0, ar, ep, wp, 0);
  for (int jb = 0; jb < NN; jb += 64) {
    load_tile(t1, ar, ep, wp, jb + 32);
    compute_tile(t0, es, rsum, acc);
    if (jb + 64 < NN) load_tile(t0, ar, ep, wp, jb + 64);
    compute_tile(t1, es, rsum, acc);
  }

  // full row sums: lane groups g=0..3 hold partial sums for row il
  rsum += __shfl_xor(rsum, 16);
  rsum += __shfl_xor(rsum, 32);

  // C/D layout: col f = lane&15, row i = 4*(lane>>4) + r
#pragma unroll
  for (int r = 0; r < 4; ++r) {
    float s = __shfl(rsum, g * 4 + r);   // row-sum of row (4g + r)
    float inv = 1.0f / s;
#pragma unroll
    for (int ft = 0; ft < 4; ++ft) {
      float v = acc[ft][r] * inv;
      v = (v > 0.f) ? v : (__builtin_amdgcn_exp2f(v * LOG2E) - 1.0f);  // ELU
      atted[(size_t)(i0 + g * 4 + r) * 256 + hd * 64 + ft * 16 + il] = v;
    }
  }
}

// ---------------------------------------------------------------------------
// Kernel 3: out = atted[8192,256] @ fc_w[64,256]^T + fc_b
// ---------------------------------------------------------------------------
__global__ __launch_bounds__(256) void k_fc(
    const float* __restrict__ atted, const float* __restrict__ fcw,
    const float* __restrict__ fcb, float* __restrict__ out)
{
  __shared__ float ws[256 * 65];  // fcw transposed: ws[c*65 + o]
  const int tid = threadIdx.x;
  for (int idx = tid; idx < 64 * 256; idx += 256) {
    int o = idx >> 8, c = idx & 255;
    ws[c * 65 + o] = fcw[idx];
  }
  __syncthreads();

  const int w = tid >> 6, o = tid & 63;
  const int ibase = blockIdx.x * 64 + w * 16;
  float acc[16];
#pragma unroll
  for (int m = 0; m < 16; ++m) acc[m] = 0.f;

  const float* ap = atted + (size_t)ibase * 256;
  for (int c4 = 0; c4 < 64; ++c4) {
    float w0 = ws[(c4 * 4 + 0) * 65 + o];
    float w1 = ws[(c4 * 4 + 1) * 65 + o];
    float w2 = ws[(c4 * 4 + 2) * 65 + o];
    float w3 = ws[(c4 * 4 + 3) * 65 + o];
#pragma unroll
    for (int m = 0; m < 16; ++m) {
      fx4 hv = *(const fx4*)(ap + m * 256 + c4 * 4);
      acc[m] += hv[0] * w0 + hv[1] * w1 + hv[2] * w2 + hv[3] * w3;
    }
  }
  const float bo = fcb[o];
#pragma unroll
  for (int m = 0; m < 16; ++m)
    out[(size_t)(ibase + m) * 64 + o] = acc[m] + bo;
}

extern "C" void kernel_launch(void* const* d_in, const int* in_sizes, int n_in,
                              void* d_out, int out_size, void* d_ws, size_t ws_size,
                              hipStream_t stream) {
  (void)in_sizes; (void)n_in; (void)out_size; (void)ws_size;
  const float* h   = (const float*)d_in[0];
  const int*   adj = (const int*)d_in[1];
  const float* W   = (const float*)d_in[2];
  const float* a1  = (const float*)d_in[3];
  const float* a2  = (const float*)d_in[4];
  const float* fcw = (const float*)d_in[5];
  const float* fcb = (const float*)d_in[6];
  float* out = (float*)d_out;

  char* base = (char*)d_ws;
  unsigned short* whsw = (unsigned short*)base;                  // 4 MiB bf16
  float* esrc = (float*)(base + 4194304);                        // 128 KiB
  float* edst = (float*)(base + 4194304 + 131072);               // 128 KiB
  float* atted = (float*)(base + 4194304 + 262144);              // 8 MiB

  k_wh<<<dim3(512), dim3(256), 0, stream>>>(h, W, a1, a2, whsw, esrc, edst);
  k_attn<<<dim3(512), dim3(256), 0, stream>>>(adj, whsw, esrc, edst, atted);
  k_fc<<<dim3(128), dim3(256), 0, stream>>>(atted, fcw, fcb, out);
}

// Round 2
// 283.207 us; speedup vs baseline: 1.1640x; 1.1640x over previous
//
#include <hip/hip_runtime.h>
#include <hip/hip_bf16.h>

#define NN 8192
#define NHEADS 4
#define OUTF 64
#define NCHUNK 4
#define CHUNK 2048
#define LOG2E 1.4426950408889634f

typedef __bf16 bf16x8 __attribute__((ext_vector_type(8)));
typedef float fx4 __attribute__((ext_vector_type(4)));
typedef int ix4 __attribute__((ext_vector_type(4)));
typedef unsigned short ushort8 __attribute__((ext_vector_type(8)));

// ---------------------------------------------------------------------------
// Kernel 1: Wh = h @ W[hd]  (fp32), emit:
//   - esrc[hd][i] = (Wh[i]·a1[hd]) * log2e
//   - edst[hd][i] = (Wh[i]·a2[hd]) * log2e
//   - whsw: bf16 Wh^T pre-swizzled into MFMA-16x16x32 B-fragment order:
//       idx = hd*524288 + (j>>5)*2048 + (f>>4)*512 + ((f&15) + 16*((j>>3)&3))*8 + (j&7)
// ---------------------------------------------------------------------------
__global__ __launch_bounds__(256) void k_wh(
    const float* __restrict__ h, const float* __restrict__ W,
    const float* __restrict__ a1, const float* __restrict__ a2,
    unsigned short* __restrict__ whsw, float* __restrict__ esrc,
    float* __restrict__ edst)
{
  __shared__ float ws[64 * 260];  // W[hd] transposed: ws[o*260 + k]
  const int tid = threadIdx.x;
  const int hd = blockIdx.x >> 7;
  const int i0 = (blockIdx.x & 127) << 6;   // 64 rows per block

  const float* Wp = W + hd * (256 * 64);
  for (int idx = tid; idx < 256 * 64; idx += 256) {
    int k = idx >> 6, o = idx & 63;
    ws[o * 260 + k] = Wp[idx];
  }
  __syncthreads();

  const int w = tid >> 6, o = tid & 63;     // wave w handles rows ibase..ibase+15, col o
  const int ibase = i0 + w * 16;
  float acc[16];
#pragma unroll
  for (int m = 0; m < 16; ++m) acc[m] = 0.f;

  const float* hp = h + (size_t)ibase * 256;
  for (int k4 = 0; k4 < 64; ++k4) {
    fx4 wv = *(const fx4*)(&ws[o * 260 + k4 * 4]);
#pragma unroll
    for (int m = 0; m < 16; ++m) {
      fx4 hv = *(const fx4*)(hp + m * 256 + k4 * 4);
      acc[m] += hv[0] * wv[0] + hv[1] * wv[1] + hv[2] * wv[2] + hv[3] * wv[3];
    }
  }

  // esrc / edst: reduce over o (the 64 lanes)
  const float a1v = a1[hd * 64 + o], a2v = a2[hd * 64 + o];
#pragma unroll
  for (int m = 0; m < 16; ++m) {
    float s1 = acc[m] * a1v, s2 = acc[m] * a2v;
#pragma unroll
    for (int d = 1; d < 64; d <<= 1) {
      s1 += __shfl_xor(s1, d);
      s2 += __shfl_xor(s2, d);
    }
    if (o == 0) {
      esrc[hd * NN + ibase + m] = s1 * LOG2E;
      edst[hd * NN + ibase + m] = s2 * LOG2E;
    }
  }

  // swizzled bf16 store of Wh (rows ibase..+15, col o)
  size_t base = (size_t)hd * 524288 + (size_t)((i0 >> 5) + (w >> 1)) * 2048 +
                (size_t)(o >> 4) * 512;
  int ln0 = (o & 15) + 16 * ((w & 1) * 2);
  ushort8 pk0, pk1;
#pragma unroll
  for (int m = 0; m < 8; ++m) {
    pk0[m] = __builtin_bit_cast(unsigned short, (__bf16)acc[m]);
    pk1[m] = __builtin_bit_cast(unsigned short, (__bf16)acc[m + 8]);
  }
  *(ushort8*)(whsw + base + (size_t)ln0 * 8) = pk0;
  *(ushort8*)(whsw + base + (size_t)(ln0 + 16) * 8) = pk1;
}

// ---------------------------------------------------------------------------
// Kernel 2: masked softmax (unnormalized) + PV via mfma_f32_16x16x32_bf16.
// Grid: 1024 blocks = 256 row-tiles (32 rows) x 4 j-chunks. Block = 4 waves
// (one per head). Each wave: 2 row-sets of 16 rows sharing B-fragments/edst.
// Writes raw partial sums (pacc) + partial row sums (psum); normalization,
// ELU and the fc layer happen in k_fc.
// ---------------------------------------------------------------------------
struct Tile {
  ix4 a00, a01, a10, a11;   // adj for row-set 0 / 1
  fx4 e0, e1;               // edst (shared)
  bf16x8 b0, b1, b2, b3;    // Wh^T B-fragments (shared)
};

__device__ __forceinline__ void load_tile(Tile& t, const int* ar0, const int* ar1,
                                          const float* ep, const unsigned short* wp,
                                          int jb)
{
  t.a00 = *(const ix4*)(ar0 + jb);
  t.a01 = *(const ix4*)(ar0 + jb + 4);
  t.a10 = *(const ix4*)(ar1 + jb);
  t.a11 = *(const ix4*)(ar1 + jb + 4);
  t.e0 = *(const fx4*)(ep + jb);
  t.e1 = *(const fx4*)(ep + jb + 4);
  const unsigned short* wq = wp + (size_t)(jb >> 5) * 2048;
  t.b0 = *(const bf16x8*)(wq);
  t.b1 = *(const bf16x8*)(wq + 512);
  t.b2 = *(const bf16x8*)(wq + 1024);
  t.b3 = *(const bf16x8*)(wq + 1536);
}

__device__ __forceinline__ void compute_tile(const Tile& t, float es0, float es1,
                                             float& rs0, float& rs1,
                                             fx4* acc0, fx4* acc1)
{
  float p0[8], p1[8];
#pragma unroll
  for (int e = 0; e < 8; ++e) {
    float ed = (e < 4) ? t.e0[e] : t.e1[e - 4];
    int av0 = (e < 4) ? t.a00[e] : t.a01[e - 4];
    int av1 = (e < 4) ? t.a10[e] : t.a11[e - 4];
    float x0 = es0 + ed, x1 = es1 + ed;          // already scaled by log2e
    float l0 = fmaxf(x0, 0.2f * x0);             // leakyrelu
    float l1 = fmaxf(x1, 0.2f * x1);
    float q0 = __builtin_amdgcn_exp2f(l0);
    float q1 = __builtin_amdgcn_exp2f(l1);
    p0[e] = (av0 > 0) ? q0 : 0.0f;
    p1[e] = (av1 > 0) ? q1 : 0.0f;
  }
  rs0 += ((p0[0] + p0[1]) + (p0[2] + p0[3])) + ((p0[4] + p0[5]) + (p0[6] + p0[7]));
  rs1 += ((p1[0] + p1[1]) + (p1[2] + p1[3])) + ((p1[4] + p1[5]) + (p1[6] + p1[7]));
  bf16x8 af0, af1;
#pragma unroll
  for (int e = 0; e < 8; ++e) { af0[e] = (__bf16)p0[e]; af1[e] = (__bf16)p1[e]; }
  acc0[0] = __builtin_amdgcn_mfma_f32_16x16x32_bf16(af0, t.b0, acc0[0], 0, 0, 0);
  acc0[1] = __builtin_amdgcn_mfma_f32_16x16x32_bf16(af0, t.b1, acc0[1], 0, 0, 0);
  acc0[2] = __builtin_amdgcn_mfma_f32_16x16x32_bf16(af0, t.b2, acc0[2], 0, 0, 0);
  acc0[3] = __builtin_amdgcn_mfma_f32_16x16x32_bf16(af0, t.b3, acc0[3], 0, 0, 0);
  acc1[0] = __builtin_amdgcn_mfma_f32_16x16x32_bf16(af1, t.b0, acc1[0], 0, 0, 0);
  acc1[1] = __builtin_amdgcn_mfma_f32_16x16x32_bf16(af1, t.b1, acc1[1], 0, 0, 0);
  acc1[2] = __builtin_amdgcn_mfma_f32_16x16x32_bf16(af1, t.b2, acc1[2], 0, 0, 0);
  acc1[3] = __builtin_amdgcn_mfma_f32_16x16x32_bf16(af1, t.b3, acc1[3], 0, 0, 0);
}

__global__ __launch_bounds__(256) void k_attn(
    const int* __restrict__ adj, const unsigned short* __restrict__ whsw,
    const float* __restrict__ esrc, const float* __restrict__ edst,
    float* __restrict__ pacc, float* __restrict__ psum)
{
  const int lane = threadIdx.x & 63;
  const int hd = threadIdx.x >> 6;          // wave = head
  const int ci = blockIdx.x & 3;            // j-chunk
  const int ri = blockIdx.x >> 2;           // 32-row tile
  const int i0 = ri << 5;
  const int j0 = ci * CHUNK;
  const int il = lane & 15;
  const int g = lane >> 4;

  const float es0 = esrc[hd * NN + i0 + il];
  const float es1 = esrc[hd * NN + i0 + 16 + il];
  const int* ar0 = adj + (size_t)(i0 + il) * NN + j0 + g * 8;
  const int* ar1 = adj + (size_t)(i0 + 16 + il) * NN + j0 + g * 8;
  const float* ep = edst + hd * NN + j0 + g * 8;
  const unsigned short* wp = whsw + (size_t)hd * 524288 +
                             (size_t)(j0 >> 5) * 2048 + (size_t)lane * 8;

  fx4 acc0[4] = {}, acc1[4] = {};
  float rs0 = 0.f, rs1 = 0.f;

  Tile t0, t1;
  load_tile(t0, ar0, ar1, ep, wp, 0);
  for (int jb = 0; jb < CHUNK; jb += 64) {
    load_tile(t1, ar0, ar1, ep, wp, jb + 32);
    compute_tile(t0, es0, es1, rs0, rs1, acc0, acc1);
    if (jb + 64 < CHUNK) load_tile(t0, ar0, ar1, ep, wp, jb + 64);
    compute_tile(t1, es0, es1, rs0, rs1, acc0, acc1);
  }

  // partial row sums: reduce over the 4 lane groups
  rs0 += __shfl_xor(rs0, 16); rs0 += __shfl_xor(rs0, 32);
  rs1 += __shfl_xor(rs1, 16); rs1 += __shfl_xor(rs1, 32);
  if (g == 0) {
    psum[(size_t)(ci * NHEADS + hd) * NN + i0 + il] = rs0;
    psum[(size_t)(ci * NHEADS + hd) * NN + i0 + 16 + il] = rs1;
  }

  // raw accumulator store. C/D layout: col f = lane&15, row i = 4*(lane>>4)+r
  float* pc = pacc + (size_t)ci * NN * 256;
#pragma unroll
  for (int r = 0; r < 4; ++r) {
#pragma unroll
    for (int ft = 0; ft < 4; ++ft) {
      pc[(size_t)(i0 + g * 4 + r) * 256 + hd * 64 + ft * 16 + il] = acc0[ft][r];
      pc[(size_t)(i0 + 16 + g * 4 + r) * 256 + hd * 64 + ft * 16 + il] = acc1[ft][r];
    }
  }
}

// ---------------------------------------------------------------------------
// Kernel 3: combine chunks -> normalize -> ELU -> out = att @ fc_w^T + fc_b
// Block = 64 rows; att tile staged in LDS.
// ---------------------------------------------------------------------------
__global__ __launch_bounds__(256) void k_fc(
    const float* __restrict__ pacc, const float* __restrict__ psum,
    const float* __restrict__ fcw, const float* __restrict__ fcb,
    float* __restrict__ out)
{
  __shared__ float ws[256 * 65];    // fcw transposed: ws[c*65 + o]
  __shared__ float ash[64 * 260];   // combined att rows
  __shared__ float inv[64 * 4];     // 1/rowsum per (row, head)
  const int tid = threadIdx.x;
  const int i0 = blockIdx.x * 64;

  for (int idx = tid; idx < 64 * 256; idx += 256) {
    int o = idx >> 8, c = idx & 255;
    ws[c * 65 + o] = fcw[idx];
  }
  {
    int m = tid >> 2, hh = tid & 3;
    float s = 0.f;
#pragma unroll
    for (int ci = 0; ci < NCHUNK; ++ci)
      s += psum[(size_t)(ci * NHEADS + hh) * NN + i0 + m];
    inv[m * 4 + hh] = 1.0f / s;
  }
  __syncthreads();

  for (int idx = tid; idx < 64 * 64; idx += 256) {
    int m = idx >> 6, q = idx & 63;       // q = fx4 index within the 256 feats
    int hh = q >> 4;
    size_t off = (size_t)(i0 + m) * 256 + q * 4;
    fx4 v = {};
#pragma unroll
    for (int ci = 0; ci < NCHUNK; ++ci) {
      fx4 a = *(const fx4*)(pacc + (size_t)ci * NN * 256 + off);
      v[0] += a[0]; v[1] += a[1]; v[2] += a[2]; v[3] += a[3];
    }
    float iv = inv[m * 4 + hh];
#pragma unroll
    for (int j = 0; j < 4; ++j) {
      float x = v[j] * iv;
      x = (x > 0.f) ? x : (__builtin_amdgcn_exp2f(x * LOG2E) - 1.0f);  // ELU
      ash[m * 260 + q * 4 + j] = x;
    }
  }
  __syncthreads();

  const int w = tid >> 6, o = tid & 63;
  float acc[16];
#pragma unroll
  for (int m = 0; m < 16; ++m) acc[m] = 0.f;

  for (int c4 = 0; c4 < 64; ++c4) {
    float w0 = ws[(c4 * 4 + 0) * 65 + o];
    float w1 = ws[(c4 * 4 + 1) * 65 + o];
    float w2 = ws[(c4 * 4 + 2) * 65 + o];
    float w3 = ws[(c4 * 4 + 3) * 65 + o];
#pragma unroll
    for (int m = 0; m < 16; ++m) {
      fx4 hv = *(const fx4*)(&ash[(w * 16 + m) * 260 + c4 * 4]);
      acc[m] += hv[0] * w0 + hv[1] * w1 + hv[2] * w2 + hv[3] * w3;
    }
  }
  const float bo = fcb[o];
#pragma unroll
  for (int m = 0; m < 16; ++m)
    out[(size_t)(i0 + w * 16 + m) * 64 + o] = acc[m] + bo;
}

extern "C" void kernel_launch(void* const* d_in, const int* in_sizes, int n_in,
                              void* d_out, int out_size, void* d_ws, size_t ws_size,
                              hipStream_t stream) {
  (void)in_sizes; (void)n_in; (void)out_size; (void)ws_size;
  const float* h   = (const float*)d_in[0];
  const int*   adj = (const int*)d_in[1];
  const float* W   = (const float*)d_in[2];
  const float* a1  = (const float*)d_in[3];
  const float* a2  = (const float*)d_in[4];
  const float* fcw = (const float*)d_in[5];
  const float* fcb = (const float*)d_in[6];
  float* out = (float*)d_out;

  char* base = (char*)d_ws;
  unsigned short* whsw = (unsigned short*)base;                  // 4 MiB bf16
  float* esrc = (float*)(base + (4u << 20));                     // 128 KiB
  float* edst = (float*)(base + (4u << 20) + (128u << 10));      // 128 KiB
  float* pacc = (float*)(base + (4u << 20) + (256u << 10));      // 32 MiB
  float* psum = (float*)(base + (36u << 20) + (256u << 10));     // 512 KiB

  k_wh<<<dim3(512), dim3(256), 0, stream>>>(h, W, a1, a2, whsw, esrc, edst);
  k_attn<<<dim3(1024), dim3(256), 0, stream>>>(adj, whsw, esrc, edst, pacc, psum);
  k_fc<<<dim3(128), dim3(256), 0, stream>>>(pacc, psum, fcw, fcb, out);
}

// Round 3
// 238.808 us; speedup vs baseline: 1.3804x; 1.1859x over previous
//
#include <hip/hip_runtime.h>
#include <hip/hip_bf16.h>

#define NN 8192
#define NHEADS 4
#define OUTF 64
#define NCHUNK 2
#define CHUNK 4096
#define ROWS 32
#define LOG2E 1.4426950408889634f

typedef __bf16 bf16x8 __attribute__((ext_vector_type(8)));
typedef float fx4 __attribute__((ext_vector_type(4)));
typedef unsigned short ushort8 __attribute__((ext_vector_type(8)));

// ---------------------------------------------------------------------------
// Kernel 1: Wh = h @ W[hd] (fp32). Outputs:
//   E1[hd][i]=exp(es), E2[hd][i]=exp(0.2*es), F1[hd][j]=exp(ed), F2=exp(0.2*ed)
//   whsw: bf16 Wh^T pre-swizzled into MFMA-16x16x32 B-fragment order.
// ---------------------------------------------------------------------------
__global__ __launch_bounds__(256) void k_wh(
    const float* __restrict__ h, const float* __restrict__ W,
    const float* __restrict__ a1, const float* __restrict__ a2,
    unsigned short* __restrict__ whsw, float* __restrict__ E1,
    float* __restrict__ E2, float* __restrict__ F1, float* __restrict__ F2)
{
  __shared__ float ws[64 * 260];  // W[hd] transposed: ws[o*260 + k]
  const int tid = threadIdx.x;
  const int hd = blockIdx.x >> 7;
  const int i0 = (blockIdx.x & 127) << 6;   // 64 rows per block

  const float* Wp = W + hd * (256 * 64);
  for (int idx = tid; idx < 256 * 64; idx += 256) {
    int k = idx >> 6, o = idx & 63;
    ws[o * 260 + k] = Wp[idx];
  }
  __syncthreads();

  const int w = tid >> 6, o = tid & 63;     // wave w: rows ibase..+15, col o
  const int ibase = i0 + w * 16;
  float acc[16];
#pragma unroll
  for (int m = 0; m < 16; ++m) acc[m] = 0.f;

  const float* hp = h + (size_t)ibase * 256;
  for (int k4 = 0; k4 < 64; ++k4) {
    fx4 wv = *(const fx4*)(&ws[o * 260 + k4 * 4]);
#pragma unroll
    for (int m = 0; m < 16; ++m) {
      fx4 hv = *(const fx4*)(hp + m * 256 + k4 * 4);
      acc[m] += hv[0] * wv[0] + hv[1] * wv[1] + hv[2] * wv[2] + hv[3] * wv[3];
    }
  }

  const float a1v = a1[hd * 64 + o], a2v = a2[hd * 64 + o];
#pragma unroll
  for (int m = 0; m < 16; ++m) {
    float s1 = acc[m] * a1v, s2 = acc[m] * a2v;
#pragma unroll
    for (int d = 1; d < 64; d <<= 1) {
      s1 += __shfl_xor(s1, d);
      s2 += __shfl_xor(s2, d);
    }
    if (o == 0) {
      int ix = hd * NN + ibase + m;
      E1[ix] = __builtin_amdgcn_exp2f(s1 * LOG2E);
      E2[ix] = __builtin_amdgcn_exp2f(0.2f * s1 * LOG2E);
      F1[ix] = __builtin_amdgcn_exp2f(s2 * LOG2E);
      F2[ix] = __builtin_amdgcn_exp2f(0.2f * s2 * LOG2E);
    }
  }

  // swizzled bf16 store of Wh (rows ibase..+15, col o)
  size_t base = (size_t)hd * 524288 + (size_t)((i0 >> 5) + (w >> 1)) * 2048 +
                (size_t)(o >> 4) * 512;
  int ln0 = (o & 15) + 16 * ((w & 1) * 2);
  ushort8 pk0, pk1;
#pragma unroll
  for (int m = 0; m < 8; ++m) {
    pk0[m] = __builtin_bit_cast(unsigned short, (__bf16)acc[m]);
    pk1[m] = __builtin_bit_cast(unsigned short, (__bf16)acc[m + 8]);
  }
  *(ushort8*)(whsw + base + (size_t)ln0 * 8) = pk0;
  *(ushort8*)(whsw + base + (size_t)(ln0 + 16) * 8) = pk1;
}

// ---------------------------------------------------------------------------
// Kernel 2: fused adj->bitmask (LDS) + masked unnormalized softmax + PV MFMA.
// Grid: 512 blocks = 256 row-tiles (32 rows) x 2 j-chunks (4096). 4 waves =
// 4 heads. p = max(E1_i*F1_j, E2_i*F2_j) (== exp(leakyrelu(es+ed)) exactly),
// masked via LDS bitmask; rowsum via a 5th MFMA against all-ones B.
// ---------------------------------------------------------------------------
struct Tile {
  fx4 f1a, f1b, f2a, f2b;   // F1/F2 slices (per lane group g)
  bf16x8 b0, b1, b2, b3;    // Wh^T B-fragments
  unsigned m0, m1;          // bitmask words for rowset 0/1
};

__device__ __forceinline__ void load_tile(Tile& t, const float* F1p,
                                          const float* F2p,
                                          const unsigned short* wp,
                                          const unsigned* bm, int il, int jb)
{
  t.f1a = *(const fx4*)(F1p + jb);
  t.f1b = *(const fx4*)(F1p + jb + 4);
  t.f2a = *(const fx4*)(F2p + jb);
  t.f2b = *(const fx4*)(F2p + jb + 4);
  const unsigned short* wq = wp + (size_t)(jb >> 5) * 2048;
  t.b0 = *(const bf16x8*)(wq);
  t.b1 = *(const bf16x8*)(wq + 512);
  t.b2 = *(const bf16x8*)(wq + 1024);
  t.b3 = *(const bf16x8*)(wq + 1536);
  const unsigned* mb = bm + (jb >> 5) * ROWS;
  t.m0 = mb[il];
  t.m1 = mb[16 + il];
}

__device__ __forceinline__ void compute_tile(const Tile& t, const float* E1r,
                                             const float* E2r, int g,
                                             const bf16x8& ones,
                                             fx4 acc[2][4], fx4* accS)
{
#pragma unroll
  for (int rs = 0; rs < 2; ++rs) {
    unsigned sm = (rs ? t.m1 : t.m0) >> (g * 8);
    float p[8];
#pragma unroll
    for (int e = 0; e < 8; ++e) {
      float f1 = (e < 4) ? t.f1a[e] : t.f1b[e - 4];
      float f2 = (e < 4) ? t.f2a[e] : t.f2b[e - 4];
      float pos = E1r[rs] * f1;
      float neg = E2r[rs] * f2;
      float pm = fmaxf(pos, neg);          // exp(leakyrelu(es+ed)) exactly
      unsigned keep = (unsigned)(((int)(sm << (31 - e))) >> 31);  // bfe_i32
      p[e] = __builtin_bit_cast(float,
                 __builtin_bit_cast(unsigned, pm) & keep);
    }
    bf16x8 af;
#pragma unroll
    for (int e = 0; e < 8; ++e) af[e] = (__bf16)p[e];
    acc[rs][0] = __builtin_amdgcn_mfma_f32_16x16x32_bf16(af, t.b0, acc[rs][0], 0, 0, 0);
    acc[rs][1] = __builtin_amdgcn_mfma_f32_16x16x32_bf16(af, t.b1, acc[rs][1], 0, 0, 0);
    acc[rs][2] = __builtin_amdgcn_mfma_f32_16x16x32_bf16(af, t.b2, acc[rs][2], 0, 0, 0);
    acc[rs][3] = __builtin_amdgcn_mfma_f32_16x16x32_bf16(af, t.b3, acc[rs][3], 0, 0, 0);
    accS[rs] = __builtin_amdgcn_mfma_f32_16x16x32_bf16(af, ones, accS[rs], 0, 0, 0);
  }
}

__global__ __launch_bounds__(256) void k_attn(
    const int* __restrict__ adj, const unsigned short* __restrict__ whsw,
    const float* __restrict__ E1g, const float* __restrict__ E2g,
    const float* __restrict__ F1g, const float* __restrict__ F2g,
    float* __restrict__ pacc, float* __restrict__ psum)
{
  __shared__ unsigned bm[(CHUNK / 32) * ROWS];   // [seg32][row] : 16 KiB
  const int tid = threadIdx.x;
  const int lane = tid & 63;
  const int hd = tid >> 6;                 // wave = head
  const int ci = blockIdx.x & 1;           // j-chunk
  const int i0 = (blockIdx.x >> 1) << 5;   // 32 rows
  const int j0 = ci * CHUNK;
  const int il = lane & 15;
  const int g = lane >> 4;

  // ---- phase 1: adj region -> LDS bitmask (exactly-once adj read) ----
  {
    const int wv = hd;                     // wave index 0..3
    for (int it = 0; it < 16; ++it) {
      int tb = wv * 512 + it * 32;         // 2048 ballots total, 8-unrolled x4
#pragma unroll 4
      for (int blk = 0; blk < 4; ++blk) {
        int v[8];
#pragma unroll
        for (int u = 0; u < 8; ++u) {
          int t = tb + blk * 8 + u;
          int row = t >> 6, sg = t & 63;
          v[u] = adj[(size_t)(i0 + row) * NN + j0 + sg * 64 + lane];
        }
#pragma unroll
        for (int u = 0; u < 8; ++u) {
          int t = tb + blk * 8 + u;
          int row = t >> 6, sg = t & 63;
          unsigned long long m = __ballot(v[u] != 0);
          unsigned word = (lane == 1) ? (unsigned)(m >> 32) : (unsigned)m;
          if (lane < 2) bm[(sg * 2 + lane) * ROWS + row] = word;
        }
      }
    }
  }
  __syncthreads();

  // ---- phase 2: masked softmax + PV ----
  float E1r[2], E2r[2];
#pragma unroll
  for (int rs = 0; rs < 2; ++rs) {
    E1r[rs] = E1g[hd * NN + i0 + rs * 16 + il];
    E2r[rs] = E2g[hd * NN + i0 + rs * 16 + il];
  }
  const float* F1p = F1g + hd * NN + j0 + g * 8;
  const float* F2p = F2g + hd * NN + j0 + g * 8;
  const unsigned short* wp = whsw + (size_t)hd * 524288 +
                             (size_t)(j0 >> 5) * 2048 + (size_t)lane * 8;
  bf16x8 ones;
#pragma unroll
  for (int e = 0; e < 8; ++e) ones[e] = (__bf16)1.0f;

  fx4 acc[2][4] = {};
  fx4 accS[2] = {};

  Tile t0, t1;
  load_tile(t0, F1p, F2p, wp, bm, il, 0);
  for (int jb = 0; jb < CHUNK; jb += 64) {
    load_tile(t1, F1p, F2p, wp, bm, il, jb + 32);
    compute_tile(t0, E1r, E2r, g, ones, acc, accS);
    if (jb + 64 < CHUNK) load_tile(t0, F1p, F2p, wp, bm, il, jb + 64);
    compute_tile(t1, E1r, E2r, g, ones, acc, accS);
  }

  // partial row sums (all columns of accS equal the rowsum)
#pragma unroll
  for (int rs = 0; rs < 2; ++rs) {
    if (il == 0) {
#pragma unroll
      for (int r = 0; r < 4; ++r)
        psum[(size_t)(ci * NHEADS + hd) * NN + i0 + rs * 16 + g * 4 + r] =
            accS[rs][r];
    }
  }

  // raw accumulator store. C/D: col f = lane&15, row i = 4*(lane>>4)+r
  float* pc = pacc + (size_t)ci * NN * 256;
#pragma unroll
  for (int rs = 0; rs < 2; ++rs)
#pragma unroll
    for (int r = 0; r < 4; ++r)
#pragma unroll
      for (int ft = 0; ft < 4; ++ft)
        pc[(size_t)(i0 + rs * 16 + g * 4 + r) * 256 + hd * 64 + ft * 16 + il] =
            acc[rs][ft][r];
}

// ---------------------------------------------------------------------------
// Kernel 3: combine chunks -> normalize -> ELU -> out = att @ fc_w^T + fc_b
// 256 blocks x 32 rows.
// ---------------------------------------------------------------------------
__global__ __launch_bounds__(256) void k_fc(
    const float* __restrict__ pacc, const float* __restrict__ psum,
    const float* __restrict__ fcw, const float* __restrict__ fcb,
    float* __restrict__ out)
{
  __shared__ float ws[256 * 65];    // fcw transposed: ws[c*65 + o]
  __shared__ float ash[32 * 260];   // combined att rows
  __shared__ float inv[32 * 4];
  const int tid = threadIdx.x;
  const int i0 = blockIdx.x * 32;

  for (int idx = tid; idx < 64 * 256; idx += 256) {
    int o = idx >> 8, c = idx & 255;
    ws[c * 65 + o] = fcw[idx];
  }
  if (tid < 128) {
    int m = tid >> 2, hh = tid & 3;
    float s = 0.f;
#pragma unroll
    for (int ci = 0; ci < NCHUNK; ++ci)
      s += psum[(size_t)(ci * NHEADS + hh) * NN + i0 + m];
    inv[m * 4 + hh] = 1.0f / s;
  }
  __syncthreads();

  for (int idx = tid; idx < 32 * 64; idx += 256) {
    int m = idx >> 6, q = idx & 63;
    int hh = q >> 4;
    size_t off = (size_t)(i0 + m) * 256 + q * 4;
    fx4 v = {};
#pragma unroll
    for (int ci = 0; ci < NCHUNK; ++ci) {
      fx4 a = *(const fx4*)(pacc + (size_t)ci * NN * 256 + off);
      v[0] += a[0]; v[1] += a[1]; v[2] += a[2]; v[3] += a[3];
    }
    float iv = inv[m * 4 + hh];
#pragma unroll
    for (int j = 0; j < 4; ++j) {
      float x = v[j] * iv;
      x = (x > 0.f) ? x : (__builtin_amdgcn_exp2f(x * LOG2E) - 1.0f);  // ELU
      ash[m * 260 + q * 4 + j] = x;
    }
  }
  __syncthreads();

  const int w = tid >> 6, o = tid & 63;
  float acc[8];
#pragma unroll
  for (int m = 0; m < 8; ++m) acc[m] = 0.f;

  for (int c4 = 0; c4 < 64; ++c4) {
    float w0 = ws[(c4 * 4 + 0) * 65 + o];
    float w1 = ws[(c4 * 4 + 1) * 65 + o];
    float w2 = ws[(c4 * 4 + 2) * 65 + o];
    float w3 = ws[(c4 * 4 + 3) * 65 + o];
#pragma unroll
    for (int m = 0; m < 8; ++m) {
      fx4 hv = *(const fx4*)(&ash[(w * 8 + m) * 260 + c4 * 4]);
      acc[m] += hv[0] * w0 + hv[1] * w1 + hv[2] * w2 + hv[3] * w3;
    }
  }
  const float bo = fcb[o];
#pragma unroll
  for (int m = 0; m < 8; ++m)
    out[(size_t)(i0 + w * 8 + m) * 64 + o] = acc[m] + bo;
}

extern "C" void kernel_launch(void* const* d_in, const int* in_sizes, int n_in,
                              void* d_out, int out_size, void* d_ws, size_t ws_size,
                              hipStream_t stream) {
  (void)in_sizes; (void)n_in; (void)out_size; (void)ws_size;
  const float* h   = (const float*)d_in[0];
  const int*   adj = (const int*)d_in[1];
  const float* W   = (const float*)d_in[2];
  const float* a1  = (const float*)d_in[3];
  const float* a2  = (const float*)d_in[4];
  const float* fcw = (const float*)d_in[5];
  const float* fcb = (const float*)d_in[6];
  float* out = (float*)d_out;

  char* base = (char*)d_ws;
  unsigned short* whsw = (unsigned short*)base;            // 4 MiB
  float* E1 = (float*)(base + (4u << 20));                 // 128 KiB each
  float* E2 = (float*)(base + (4u << 20) + (128u << 10));
  float* F1 = (float*)(base + (4u << 20) + (256u << 10));
  float* F2 = (float*)(base + (4u << 20) + (384u << 10));
  float* pacc = (float*)(base + (4u << 20) + (512u << 10));          // 16 MiB
  float* psum = (float*)(base + (20u << 20) + (512u << 10));         // 256 KiB

  k_wh<<<dim3(512), dim3(256), 0, stream>>>(h, W, a1, a2, whsw, E1, E2, F1, F2);
  k_attn<<<dim3(512), dim3(256), 0, stream>>>(adj, whsw, E1, E2, F1, F2, pacc, psum);
  k_fc<<<dim3(256), dim3(256), 0, stream>>>(pacc, psum, fcw, fcb, out);
}

// Round 4
// 225.201 us; speedup vs baseline: 1.4639x; 1.0604x over previous
//
#include <hip/hip_runtime.h>
#include <hip/hip_bf16.h>

#define NN 8192
#define NHEADS 4
#define OUTF 64
#define NCHUNK 4
#define CHUNK 2048
#define ROWS 32
#define LOG2E 1.4426950408889634f

typedef __bf16 bf16x8 __attribute__((ext_vector_type(8)));
typedef float fx4 __attribute__((ext_vector_type(4)));
typedef unsigned short ushort8 __attribute__((ext_vector_type(8)));

// ---------------------------------------------------------------------------
// Kernel 1: Wh = h @ W[hd] (fp32). Outputs (log2-domain factorization):
//   R [hd][i] = 2^(-0.8*es_i*log2e)   (= exp(-0.8*es))
//   F1[hd][j] = 2^(ed_j*log2e),  F2[hd][j] = 2^(0.2*ed_j*log2e)
//   whsw: bf16 Wh^T pre-swizzled into MFMA-16x16x32 B-fragment order.
// Row-factor E1 cancels in softmax normalization, so it is never computed.
// ---------------------------------------------------------------------------
__global__ __launch_bounds__(256) void k_wh(
    const float* __restrict__ h, const float* __restrict__ W,
    const float* __restrict__ a1, const float* __restrict__ a2,
    unsigned short* __restrict__ whsw, float* __restrict__ R,
    float* __restrict__ F1, float* __restrict__ F2)
{
  __shared__ float ws[64 * 260];  // W[hd] transposed: ws[o*260 + k]
  const int tid = threadIdx.x;
  const int hd = blockIdx.x >> 7;
  const int i0 = (blockIdx.x & 127) << 6;   // 64 rows per block

  const float* Wp = W + hd * (256 * 64);
  for (int idx = tid; idx < 256 * 64; idx += 256) {
    int k = idx >> 6, o = idx & 63;
    ws[o * 260 + k] = Wp[idx];
  }
  __syncthreads();

  const int w = tid >> 6, o = tid & 63;     // wave w: rows ibase..+15, col o
  const int ibase = i0 + w * 16;
  float acc[16];
#pragma unroll
  for (int m = 0; m < 16; ++m) acc[m] = 0.f;

  const float* hp = h + (size_t)ibase * 256;
  for (int k4 = 0; k4 < 64; ++k4) {
    fx4 wv = *(const fx4*)(&ws[o * 260 + k4 * 4]);
#pragma unroll
    for (int m = 0; m < 16; ++m) {
      fx4 hv = *(const fx4*)(hp + m * 256 + k4 * 4);
      acc[m] += hv[0] * wv[0] + hv[1] * wv[1] + hv[2] * wv[2] + hv[3] * wv[3];
    }
  }

  const float a1v = a1[hd * 64 + o], a2v = a2[hd * 64 + o];
#pragma unroll
  for (int m = 0; m < 16; ++m) {
    float s1 = acc[m] * a1v, s2 = acc[m] * a2v;
#pragma unroll
    for (int d = 1; d < 64; d <<= 1) {
      s1 += __shfl_xor(s1, d);
      s2 += __shfl_xor(s2, d);
    }
    if (o == 0) {
      int ix = hd * NN + ibase + m;
      R[ix]  = __builtin_amdgcn_exp2f(-0.8f * s1 * LOG2E);
      F1[ix] = __builtin_amdgcn_exp2f(s2 * LOG2E);
      F2[ix] = __builtin_amdgcn_exp2f(0.2f * s2 * LOG2E);
    }
  }

  // swizzled bf16 store of Wh (rows ibase..+15, col o)
  size_t base = (size_t)hd * 524288 + (size_t)((i0 >> 5) + (w >> 1)) * 2048 +
                (size_t)(o >> 4) * 512;
  int ln0 = (o & 15) + 16 * ((w & 1) * 2);
  ushort8 pk0, pk1;
#pragma unroll
  for (int m = 0; m < 8; ++m) {
    pk0[m] = __builtin_bit_cast(unsigned short, (__bf16)acc[m]);
    pk1[m] = __builtin_bit_cast(unsigned short, (__bf16)acc[m + 8]);
  }
  *(ushort8*)(whsw + base + (size_t)ln0 * 8) = pk0;
  *(ushort8*)(whsw + base + (size_t)(ln0 + 16) * 8) = pk1;
}

// ---------------------------------------------------------------------------
// Kernel 2: fused adj->bitmask (LDS) + masked unnormalized softmax + PV MFMA.
// Grid: 1024 blocks = 256 row-tiles (32 rows) x 4 j-chunks (2048). 4 waves =
// 4 heads. q = max(F1_j, r_i*F2_j) masked (row factor cancels in softmax);
// rowsum via a 5th MFMA against all-ones B.
// ---------------------------------------------------------------------------
struct Tile {
  fx4 f1a, f1b, f2a, f2b;   // F1/F2 slices (per lane group g)
  bf16x8 b0, b1, b2, b3;    // Wh^T B-fragments
  unsigned m0, m1;          // bitmask words for rowset 0/1
};

__device__ __forceinline__ void load_tile(Tile& t, const float* F1p,
                                          const float* F2p,
                                          const unsigned short* wp,
                                          const unsigned* bm, int il, int jb)
{
  t.f1a = *(const fx4*)(F1p + jb);
  t.f1b = *(const fx4*)(F1p + jb + 4);
  t.f2a = *(const fx4*)(F2p + jb);
  t.f2b = *(const fx4*)(F2p + jb + 4);
  const unsigned short* wq = wp + (size_t)(jb >> 5) * 2048;
  t.b0 = *(const bf16x8*)(wq);
  t.b1 = *(const bf16x8*)(wq + 512);
  t.b2 = *(const bf16x8*)(wq + 1024);
  t.b3 = *(const bf16x8*)(wq + 1536);
  const unsigned* mb = bm + (jb >> 5) * ROWS;
  t.m0 = mb[il];
  t.m1 = mb[16 + il];
}

__device__ __forceinline__ void compute_tile(const Tile& t, const float* Rr,
                                             int g, const bf16x8& ones,
                                             fx4 acc[2][4], fx4* accS)
{
#pragma unroll
  for (int rs = 0; rs < 2; ++rs) {
    unsigned sm = (rs ? t.m1 : t.m0) >> (g * 8);
    float p[8];
#pragma unroll
    for (int e = 0; e < 8; ++e) {
      float f1 = (e < 4) ? t.f1a[e] : t.f1b[e - 4];
      float f2 = (e < 4) ? t.f2a[e] : t.f2b[e - 4];
      float pm = fmaxf(f1, Rr[rs] * f2);   // ∝ exp(leakyrelu(es+ed))
      unsigned keep = (unsigned)(((int)(sm << (31 - e))) >> 31);
      p[e] = __builtin_bit_cast(float,
                 __builtin_bit_cast(unsigned, pm) & keep);
    }
    bf16x8 af;
#pragma unroll
    for (int e = 0; e < 8; ++e) af[e] = (__bf16)p[e];
    acc[rs][0] = __builtin_amdgcn_mfma_f32_16x16x32_bf16(af, t.b0, acc[rs][0], 0, 0, 0);
    acc[rs][1] = __builtin_amdgcn_mfma_f32_16x16x32_bf16(af, t.b1, acc[rs][1], 0, 0, 0);
    acc[rs][2] = __builtin_amdgcn_mfma_f32_16x16x32_bf16(af, t.b2, acc[rs][2], 0, 0, 0);
    acc[rs][3] = __builtin_amdgcn_mfma_f32_16x16x32_bf16(af, t.b3, acc[rs][3], 0, 0, 0);
    accS[rs] = __builtin_amdgcn_mfma_f32_16x16x32_bf16(af, ones, accS[rs], 0, 0, 0);
  }
}

__global__ __launch_bounds__(256) void k_attn(
    const int* __restrict__ adj, const unsigned short* __restrict__ whsw,
    const float* __restrict__ Rg, const float* __restrict__ F1g,
    const float* __restrict__ F2g, float* __restrict__ pacc,
    float* __restrict__ psum)
{
  __shared__ unsigned bm[(CHUNK / 32) * ROWS];   // [seg32][row] : 8 KiB
  const int tid = threadIdx.x;
  const int lane = tid & 63;
  const int hd = tid >> 6;                 // wave = head
  const int ci = blockIdx.x & 3;           // j-chunk
  const int i0 = (blockIdx.x >> 2) << 5;   // 32 rows
  const int j0 = ci * CHUNK;
  const int il = lane & 15;
  const int g = lane >> 4;

  // ---- phase 1: adj region -> LDS bitmask (adj read exactly once) ----
  {
    const int wv = hd;                     // wave index 0..3
    for (int it = 0; it < 8; ++it) {
      int tb = wv * 256 + it * 32;         // 1024 ballots total
#pragma unroll 4
      for (int blk = 0; blk < 4; ++blk) {
        int v[8];
#pragma unroll
        for (int u = 0; u < 8; ++u) {
          int t = tb + blk * 8 + u;
          int row = t >> 5, sg = t & 31;
          v[u] = adj[(size_t)(i0 + row) * NN + j0 + sg * 64 + lane];
        }
#pragma unroll
        for (int u = 0; u < 8; ++u) {
          int t = tb + blk * 8 + u;
          int row = t >> 5, sg = t & 31;
          unsigned long long m = __ballot(v[u] != 0);
          unsigned word = (lane == 1) ? (unsigned)(m >> 32) : (unsigned)m;
          if (lane < 2) bm[(sg * 2 + lane) * ROWS + row] = word;
        }
      }
    }
  }
  __syncthreads();

  // ---- phase 2: masked softmax + PV ----
  float Rr[2];
#pragma unroll
  for (int rs = 0; rs < 2; ++rs)
    Rr[rs] = Rg[hd * NN + i0 + rs * 16 + il];
  const float* F1p = F1g + hd * NN + j0 + g * 8;
  const float* F2p = F2g + hd * NN + j0 + g * 8;
  const unsigned short* wp = whsw + (size_t)hd * 524288 +
                             (size_t)(j0 >> 5) * 2048 + (size_t)lane * 8;
  bf16x8 ones;
#pragma unroll
  for (int e = 0; e < 8; ++e) ones[e] = (__bf16)1.0f;

  fx4 acc[2][4] = {};
  fx4 accS[2] = {};

  Tile t0, t1;
  load_tile(t0, F1p, F2p, wp, bm, il, 0);
  for (int jb = 0; jb < CHUNK; jb += 64) {
    load_tile(t1, F1p, F2p, wp, bm, il, jb + 32);
    compute_tile(t0, Rr, g, ones, acc, accS);
    if (jb + 64 < CHUNK) load_tile(t0, F1p, F2p, wp, bm, il, jb + 64);
    compute_tile(t1, Rr, g, ones, acc, accS);
  }

  // partial row sums (all columns of accS equal the rowsum)
#pragma unroll
  for (int rs = 0; rs < 2; ++rs) {
    if (il == 0) {
#pragma unroll
      for (int r = 0; r < 4; ++r)
        psum[(size_t)(ci * NHEADS + hd) * NN + i0 + rs * 16 + g * 4 + r] =
            accS[rs][r];
    }
  }

  // raw accumulator store. C/D: col f = lane&15, row i = 4*(lane>>4)+r
  float* pc = pacc + (size_t)ci * NN * 256;
#pragma unroll
  for (int rs = 0; rs < 2; ++rs)
#pragma unroll
    for (int r = 0; r < 4; ++r)
#pragma unroll
      for (int ft = 0; ft < 4; ++ft)
        pc[(size_t)(i0 + rs * 16 + g * 4 + r) * 256 + hd * 64 + ft * 16 + il] =
            acc[rs][ft][r];
}

// ---------------------------------------------------------------------------
// Kernel 3: combine chunks -> normalize -> ELU -> out = att @ fc_w^T + fc_b
// 256 blocks x 32 rows.
// ---------------------------------------------------------------------------
__global__ __launch_bounds__(256) void k_fc(
    const float* __restrict__ pacc, const float* __restrict__ psum,
    const float* __restrict__ fcw, const float* __restrict__ fcb,
    float* __restrict__ out)
{
  __shared__ float ws[256 * 65];    // fcw transposed: ws[c*65 + o]
  __shared__ float ash[32 * 260];   // combined att rows
  __shared__ float inv[32 * 4];
  const int tid = threadIdx.x;
  const int i0 = blockIdx.x * 32;

  for (int idx = tid; idx < 64 * 256; idx += 256) {
    int o = idx >> 8, c = idx & 255;
    ws[c * 65 + o] = fcw[idx];
  }
  if (tid < 128) {
    int m = tid >> 2, hh = tid & 3;
    float s = 0.f;
#pragma unroll
    for (int ci = 0; ci < NCHUNK; ++ci)
      s += psum[(size_t)(ci * NHEADS + hh) * NN + i0 + m];
    inv[m * 4 + hh] = 1.0f / s;
  }
  __syncthreads();

  for (int idx = tid; idx < 32 * 64; idx += 256) {
    int m = idx >> 6, q = idx & 63;
    int hh = q >> 4;
    size_t off = (size_t)(i0 + m) * 256 + q * 4;
    fx4 v = {};
#pragma unroll
    for (int ci = 0; ci < NCHUNK; ++ci) {
      fx4 a = *(const fx4*)(pacc + (size_t)ci * NN * 256 + off);
      v[0] += a[0]; v[1] += a[1]; v[2] += a[2]; v[3] += a[3];
    }
    float iv = inv[m * 4 + hh];
#pragma unroll
    for (int j = 0; j < 4; ++j) {
      float x = v[j] * iv;
      x = (x > 0.f) ? x : (__builtin_amdgcn_exp2f(x * LOG2E) - 1.0f);  // ELU
      ash[m * 260 + q * 4 + j] = x;
    }
  }
  __syncthreads();

  const int w = tid >> 6, o = tid & 63;
  float acc[8];
#pragma unroll
  for (int m = 0; m < 8; ++m) acc[m] = 0.f;

  for (int c4 = 0; c4 < 64; ++c4) {
    float w0 = ws[(c4 * 4 + 0) * 65 + o];
    float w1 = ws[(c4 * 4 + 1) * 65 + o];
    float w2 = ws[(c4 * 4 + 2) * 65 + o];
    float w3 = ws[(c4 * 4 + 3) * 65 + o];
#pragma unroll
    for (int m = 0; m < 8; ++m) {
      fx4 hv = *(const fx4*)(&ash[(w * 8 + m) * 260 + c4 * 4]);
      acc[m] += hv[0] * w0 + hv[1] * w1 + hv[2] * w2 + hv[3] * w3;
    }
  }
  const float bo = fcb[o];
#pragma unroll
  for (int m = 0; m < 8; ++m)
    out[(size_t)(i0 + w * 8 + m) * 64 + o] = acc[m] + bo;
}

extern "C" void kernel_launch(void* const* d_in, const int* in_sizes, int n_in,
                              void* d_out, int out_size, void* d_ws, size_t ws_size,
                              hipStream_t stream) {
  (void)in_sizes; (void)n_in; (void)out_size; (void)ws_size;
  const float* h   = (const float*)d_in[0];
  const int*   adj = (const int*)d_in[1];
  const float* W   = (const float*)d_in[2];
  const float* a1  = (const float*)d_in[3];
  const float* a2  = (const float*)d_in[4];
  const float* fcw = (const float*)d_in[5];
  const float* fcb = (const float*)d_in[6];
  float* out = (float*)d_out;

  char* base = (char*)d_ws;
  unsigned short* whsw = (unsigned short*)base;            // 4 MiB
  float* R  = (float*)(base + (4u << 20));                 // 128 KiB each
  float* F1 = (float*)(base + (4u << 20) + (128u << 10));
  float* F2 = (float*)(base + (4u << 20) + (256u << 10));
  float* pacc = (float*)(base + (4u << 20) + (512u << 10));          // 32 MiB
  float* psum = (float*)(base + (36u << 20) + (512u << 10));         // 512 KiB

  k_wh<<<dim3(512), dim3(256), 0, stream>>>(h, W, a1, a2, whsw, R, F1, F2);
  k_attn<<<dim3(1024), dim3(256), 0, stream>>>(adj, whsw, R, F1, F2, pacc, psum);
  k_fc<<<dim3(256), dim3(256), 0, stream>>>(pacc, psum, fcw, fcb, out);
}